// Round 9
// baseline (307.825 us; speedup 1.0000x reference)
//
#include <hip/hip_runtime.h>
#include <stdint.h>

#define M_ROWS 32768
#define I_DIM 256
#define H_DIM 512
#define C_DIM 1024
#define O_DIM 512

typedef __attribute__((ext_vector_type(8))) short bf16x8;
typedef __attribute__((ext_vector_type(4))) float f32x4;

// grid-barrier counters: module globals (NOT in ws -> no OOB risk; zero-init at
// module load; monotone arithmetic makes them self-consistent across graph
// iterations and rocprof replays without any re-zeroing).
__device__ unsigned g_bar[4] = {0u, 0u, 0u, 0u};

// ---------------------------------------------------------------------------
// 2-plane RNE split: x = hi + mid + r2, |r2| <= 2^-18 |x|.
// ---------------------------------------------------------------------------
__device__ __forceinline__ ushort bf16_rne(float f) {
    unsigned u = __float_as_uint(f);
    unsigned r = u + 0x7FFFu + ((u >> 16) & 1u);
    return (ushort)(r >> 16);
}
__device__ __forceinline__ float bf16_f32(ushort h) {
    return __uint_as_float(((unsigned)h) << 16);
}
__device__ __forceinline__ void split2(float f, ushort& hi, ushort& mid) {
    hi = bf16_rne(f);
    mid = bf16_rne(f - bf16_f32(hi));
}

__device__ __forceinline__ void async_ld16(const void* g, void* l) {
    __builtin_amdgcn_global_load_lds(
        (const __attribute__((address_space(1))) void*)g,
        (__attribute__((address_space(3))) void*)l, 16, 0, 0);
}

// Monotone packing: larger packed <=> (larger value, then smaller col index)
__device__ __forceinline__ unsigned long long packvi(float v, int col) {
    unsigned u = __float_as_uint(v);
    u = (u & 0x80000000u) ? ~u : (u | 0x80000000u);
    return ((unsigned long long)u << 32) | (unsigned)(~col);
}

// Swizzle: within each 64B k32-group of a row, 16B chunk kc sits at slot
// (kc + (row>>1)) & 3. Makes stride-64B fragment ds_read_b128 conflict-free
// while keeping rows DMA-contiguous (global_load_lds can't pad).
__device__ __forceinline__ int slot_of(int kc, int row) {
    return (kc + ((row >> 1) & 3)) & 3;
}

// Device-scope grid barrier. Monotone: iteration i sees g_bar[s]=256*i at
// entry; arrivals push it to 256*(i+1). Bounded spin: on co-residency failure
// produce wrong results (caught by harness) instead of a hang.
__device__ __forceinline__ void grid_sync(int s) {
    __syncthreads();
    if (threadIdx.x == 0) {
        __threadfence();                         // release my writes
        unsigned old = atomicAdd(&g_bar[s], 1u);
        unsigned target = (old & ~255u) + 256u;  // next multiple of 256
        unsigned long long guard = 0ull;
        while (atomicAdd(&g_bar[s], 0u) < target) {
            __builtin_amdgcn_s_sleep(2);
            if (++guard > 10000000ull) break;    // fail-soft
        }
        __threadfence();                         // acquire others' writes
    }
    __syncthreads();
}

// ---------------------------------------------------------------------------
// MEGA: phase A (prep) -> sync -> phase B (gemm1) -> sync -> phase C (gemm2,
// 2 tiles/block) -> sync -> phase D (gather). 256 blocks x 512 thr, 1/CU.
// All numerics bit-identical to the round-8 4-kernel pipeline.
// ---------------------------------------------------------------------------
__global__ __launch_bounds__(512, 2)
void mega(const float* X, const float* W1, const float* b1,
          const float* W2, const float* b2,
          const float* Wo, const float* bo,
          ushort* __restrict__ w1h, ushort* __restrict__ w1m,
          ushort* __restrict__ w2h, ushort* __restrict__ w2m,
          float* __restrict__ LS, unsigned long long* __restrict__ part,
          ushort* Hh, ushort* Hm, float* out) {
    __shared__ __align__(16) ushort SMEM[65536];   // 128KB, reused per phase

    const int tid = threadIdx.x;
    const int b = blockIdx.x;
    const int lane = tid & 63, wave = tid >> 6;
    const int wm = wave >> 2, wn = wave & 3;       // 2m x 4n wave grid
    const int lcol = lane & 15, quad = lane >> 4;
    const int lrow = lane >> 2, lk = (lane & 3) * 8;

    // ======================= phase A: prep =======================
    {
        // --- W1/W2 splits: 81920 chunks = 160 blocks x 512 threads ---
        int gid = b * 512 + tid;
        if (gid < 81920) {
            const int isW1 = (gid < 16384);
            const float* W = isW1 ? W1 : W2;
            ushort* hh = isW1 ? w1h : w2h;
            ushort* mm = isW1 ? w1m : w2m;
            const int K = isW1 ? I_DIM : H_DIM;
            const int cpr = K >> 3;
            int cid = isW1 ? gid : gid - 16384;
            int row = cid / cpr;
            int rem = cid - row * cpr;
            int g = rem >> 2, kc = rem & 3;
            float4 v0 = *(const float4*)(W + (size_t)cid * 8);
            float4 v1 = *(const float4*)(W + (size_t)cid * 8 + 4);
            __align__(16) ushort h[8], m[8];
            float f[8];
            *(float4*)&f[0] = v0; *(float4*)&f[4] = v1;
            #pragma unroll
            for (int j = 0; j < 8; ++j) split2(f[j], h[j], m[j]);
            size_t dst = (size_t)row * K + g * 32 + slot_of(kc, row) * 8;
            *(uint4*)(hh + dst) = *(uint4*)h;
            *(uint4*)(mm + dst) = *(uint4*)m;
        }
        // --- part zero ---
        if (gid < 32768) part[gid] = 0ull;
        // --- LS table: 4 j-columns per block, threads 0..255 (bit-identical
        //     to the old prep: same reduction tree and order) ---
        float* sred = (float*)SMEM;
        #pragma unroll 1
        for (int jj = 0; jj < 4; ++jj) {
            const int j = b * 4 + jj;
            float l0 = 0.f, l1 = 0.f, mx = 0.f;
            if (tid < 256) {
                l0 = Wo[(size_t)tid * C_DIM + j] + bo[tid];
                l1 = Wo[(size_t)(tid + 256) * C_DIM + j] + bo[tid + 256];
                mx = fmaxf(l0, l1);
                #pragma unroll
                for (int off = 1; off < 64; off <<= 1)
                    mx = fmaxf(mx, __shfl_xor(mx, off, 64));
                if ((tid & 63) == 0) sred[tid >> 6] = mx;
            }
            __syncthreads();
            mx = fmaxf(fmaxf(sred[0], sred[1]), fmaxf(sred[2], sred[3]));
            __syncthreads();
            float s = 0.f;
            if (tid < 256) {
                s = expf(l0 - mx) + expf(l1 - mx);
                #pragma unroll
                for (int off = 1; off < 64; off <<= 1)
                    s += __shfl_xor(s, off, 64);
                if ((tid & 63) == 0) sred[tid >> 6] = s;
            }
            __syncthreads();
            s = sred[0] + sred[1] + sred[2] + sred[3];
            if (tid < 256) {
                float lse = mx + logf(s);
                LS[(size_t)j * O_DIM + tid] = l0 - lse;
                LS[(size_t)j * O_DIM + tid + 256] = l1 - lse;
            }
            __syncthreads();
        }
    }
    grid_sync(0);

    // ======================= phase B: gemm1 =======================
    {
        // XCD swizzle: 256 tiles = 128 mT x 2 nT; XCD b&7 owns 16 mT.
        const int d = b;
        const int q = d >> 3;
        const int mT = ((d & 7) << 4) + (q >> 1);
        const int nT = q & 1;
        const int mBase = mT * 256;
        const int nBase = nT * 256;

        const int s_row = tid >> 1, s_half = tid & 1;
        const int sl0 = slot_of(s_half * 2,     s_row);
        const int sl1 = slot_of(s_half * 2 + 1, s_row);
        const float* xrow = X + (size_t)(mBase + s_row) * I_DIM + s_half * 16;

        const int bplane = wave >> 2;
        const int brow0 = (wave & 3) * 64;
        const ushort* wp = bplane ? w1m : w1h;
        const ushort* gks = wp + (size_t)(nBase + brow0 + lrow) * I_DIM + lk;

        f32x4 acc[8][4];
        #pragma unroll
        for (int i = 0; i < 8; ++i)
            #pragma unroll
            for (int j = 0; j < 4; ++j)
                acc[i][j] = (f32x4){0.f, 0.f, 0.f, 0.f};

        int aoff[8], boff[4];
        #pragma unroll
        for (int t = 0; t < 8; ++t) {
            int ra = wm * 128 + t * 16 + lcol;
            aoff[t] = ra * 32 + slot_of(quad, ra) * 8;
        }
        #pragma unroll
        for (int t = 0; t < 4; ++t) {
            int rb = wn * 64 + t * 16 + lcol;
            boff[t] = rb * 32 + slot_of(quad, rb) * 8;
        }

        auto loadX = [&](float* f, int k0) {
            const float* ap = xrow + k0;
            *(float4*)&f[0]  = ((const float4*)ap)[0];
            *(float4*)&f[4]  = ((const float4*)ap)[1];
            *(float4*)&f[8]  = ((const float4*)ap)[2];
            *(float4*)&f[12] = ((const float4*)ap)[3];
        };
        auto stageB = [&](int buf, int k0) {
            ushort* bb = SMEM + 32768 + buf * 16384 + bplane * 8192 + brow0 * 32;
            #pragma unroll
            for (int j = 0; j < 4; ++j)
                async_ld16(gks + k0 + (size_t)(j * 16) * I_DIM, bb + j * 512);
        };
        auto writeA = [&](int buf, const float* f) {
            ushort* a0 = SMEM + buf * 16384;
            ushort* a1 = a0 + 8192;
            bf16x8 h0, h1, m0, m1;
            #pragma unroll
            for (int j = 0; j < 8; ++j) {
                ushort hu, mu;
                split2(f[j], hu, mu);
                h0[j] = (short)hu; m0[j] = (short)mu;
                split2(f[j + 8], hu, mu);
                h1[j] = (short)hu; m1[j] = (short)mu;
            }
            *(bf16x8*)&a0[s_row * 32 + sl0 * 8] = h0;
            *(bf16x8*)&a0[s_row * 32 + sl1 * 8] = h1;
            *(bf16x8*)&a1[s_row * 32 + sl0 * 8] = m0;
            *(bf16x8*)&a1[s_row * 32 + sl1 * 8] = m1;
        };

        {
            float fx[16];
            loadX(fx, 0);
            stageB(0, 0);
            writeA(0, fx);
        }
        asm volatile("s_waitcnt lgkmcnt(0)" ::: "memory");
        asm volatile("s_waitcnt vmcnt(0)" ::: "memory");
        __builtin_amdgcn_s_barrier();
        __builtin_amdgcn_sched_barrier(0);

        const int NK = I_DIM / 32;   // 8
        #pragma unroll 2
        for (int ks = 0; ks < NK; ++ks) {
            const int cur = ks & 1;
            const bool more = (ks + 1 < NK);
            const ushort* Ac0 = SMEM + cur * 16384;
            const ushort* Ac1 = Ac0 + 8192;
            const ushort* Bc0 = SMEM + 32768 + cur * 16384;
            const ushort* Bc1 = Bc0 + 8192;

            float fn[16];
            if (more) {
                loadX(fn, (ks + 1) * 32);
                stageB(cur ^ 1, (ks + 1) * 32);
                __builtin_amdgcn_sched_barrier(0);
            }

            bf16x8 bh[4], bm[4];
            #pragma unroll
            for (int nt = 0; nt < 4; ++nt) {
                bh[nt] = *(const bf16x8*)&Bc0[boff[nt]];
                bm[nt] = *(const bf16x8*)&Bc1[boff[nt]];
            }
            #pragma unroll
            for (int half = 0; half < 2; ++half) {
                bf16x8 ah[4], am[4];
                #pragma unroll
                for (int mt = 0; mt < 4; ++mt) {
                    ah[mt] = *(const bf16x8*)&Ac0[aoff[half * 4 + mt]];
                    am[mt] = *(const bf16x8*)&Ac1[aoff[half * 4 + mt]];
                }
                __builtin_amdgcn_s_setprio(1);
                #pragma unroll
                for (int nt = 0; nt < 4; ++nt) {
                    #pragma unroll
                    for (int mt = 0; mt < 4; ++mt) {
                        f32x4 a = acc[half * 4 + mt][nt];
                        a = __builtin_amdgcn_mfma_f32_16x16x32_bf16(am[mt], bh[nt], a, 0, 0, 0);
                        a = __builtin_amdgcn_mfma_f32_16x16x32_bf16(ah[mt], bm[nt], a, 0, 0, 0);
                        a = __builtin_amdgcn_mfma_f32_16x16x32_bf16(ah[mt], bh[nt], a, 0, 0, 0);
                        acc[half * 4 + mt][nt] = a;
                    }
                }
                __builtin_amdgcn_s_setprio(0);
            }

            if (more) writeA(cur ^ 1, fn);
            asm volatile("s_waitcnt lgkmcnt(0)" ::: "memory");
            if (more)
                asm volatile("s_waitcnt vmcnt(0)" ::: "memory");
            __builtin_amdgcn_s_barrier();
            __builtin_amdgcn_sched_barrier(0);
        }

        // epilogue: bias+relu+split, staged across 128KB SMEM, uint4 out
        #pragma unroll
        for (int plane = 0; plane < 2; ++plane) {
            __syncthreads();
            #pragma unroll
            for (int nt = 0; nt < 4; ++nt) {
                int colRel = wn * 64 + nt * 16 + lcol;
                int g = colRel >> 5, kc = (colRel >> 3) & 3, pos = colRel & 7;
                float bias = b1[nBase + colRel];
                #pragma unroll
                for (int mt = 0; mt < 8; ++mt) {
                    #pragma unroll
                    for (int r = 0; r < 4; ++r) {
                        int rowRel = wm * 128 + mt * 16 + quad * 4 + r;
                        float v = fmaxf(acc[mt][nt][r] + bias, 0.f);
                        ushort hu, mu;
                        split2(v, hu, mu);
                        SMEM[rowRel * 256 + g * 32 + slot_of(kc, rowRel) * 8 + pos]
                            = plane ? mu : hu;
                    }
                }
            }
            __syncthreads();
            ushort* dstp = plane ? Hm : Hh;
            #pragma unroll
            for (int l2 = 0; l2 < 16; ++l2) {
                int c = l2 * 512 + tid;
                int row = c >> 5, idx = c & 31;
                *(uint4*)(dstp + (size_t)(mBase + row) * H_DIM + nBase + idx * 8)
                    = *(const uint4*)&SMEM[row * 256 + idx * 8];
            }
        }
    }
    grid_sync(1);

    // ======================= phase C: gemm2 (2 tiles) =======================
    {
        ushort* As_base = SMEM;            // [buf][plane][8192] = 64KB
        ushort* Bs_base = SMEM + 32768;    // [buf][plane][8192] = 64KB

        int aoff[8], boff[4];
        #pragma unroll
        for (int t = 0; t < 8; ++t) {
            int ra = wm * 128 + t * 16 + lcol;
            aoff[t] = ra * 32 + slot_of(quad, ra) * 8;
        }
        #pragma unroll
        for (int t = 0; t < 4; ++t) {
            int rb = wn * 64 + t * 16 + lcol;
            boff[t] = rb * 32 + slot_of(quad, rb) * 8;
        }

        const int m_id = wave >> 1;
        const int shalf = wave & 1;

        #pragma unroll 1
        for (int rnd = 0; rnd < 2; ++rnd) {
            // XCD swizzle over 512 tiles; this block's XCD fixed, mT-slice
            // contiguous, nT fastest (same locality as the split kernel).
            const int d = b + rnd * 256;
            const int l = d >> 3;
            const int mT = ((d & 7) << 4) + (l >> 2);
            const int nT = l & 3;
            const int mBase = mT * 256;
            const int nBase = nT * 256;

            const ushort* gsrc;
            ushort* lbase;
            switch (m_id) {
                case 0:  gsrc = Hh  + (size_t)mBase * H_DIM; lbase = As_base;        break;
                case 1:  gsrc = Hm  + (size_t)mBase * H_DIM; lbase = As_base + 8192; break;
                case 2:  gsrc = w2h + (size_t)nBase * H_DIM; lbase = Bs_base;        break;
                default: gsrc = w2m + (size_t)nBase * H_DIM; lbase = Bs_base + 8192; break;
            }
            ushort* l0 = lbase + shalf * 4096;
            ushort* l1 = lbase + 16384 + shalf * 4096;
            const ushort* gks = gsrc + (size_t)(shalf * 128 + lrow) * H_DIM + lk;

            f32x4 acc[8][4];
            #pragma unroll
            for (int i = 0; i < 8; ++i)
                #pragma unroll
                for (int j = 0; j < 4; ++j)
                    acc[i][j] = (f32x4){0.f, 0.f, 0.f, 0.f};

            auto stage = [&](ushort* lb, int k0) {
                #pragma unroll
                for (int j = 0; j < 8; ++j)
                    async_ld16(gks + k0 + (size_t)(j * 16) * H_DIM, lb + j * 512);
            };

            __syncthreads();   // prior SMEM use (phase B / prior round) done
            stage(l0, 0);
            asm volatile("s_waitcnt vmcnt(0)" ::: "memory");
            __builtin_amdgcn_s_barrier();
            __builtin_amdgcn_sched_barrier(0);

            const int NK = H_DIM / 32;   // 16
            #pragma unroll 2
            for (int ks = 0; ks < NK; ++ks) {
                const int cur = ks & 1;
                if (ks < NK - 1) {
                    stage(cur ? l0 : l1, (ks + 1) * 32);
                    __builtin_amdgcn_sched_barrier(0);
                }
                const ushort* Ac0 = As_base + cur * 16384;
                const ushort* Ac1 = Ac0 + 8192;
                const ushort* Bc0 = Bs_base + cur * 16384;
                const ushort* Bc1 = Bc0 + 8192;

                bf16x8 bh[4], bm[4];
                #pragma unroll
                for (int nt = 0; nt < 4; ++nt) {
                    bh[nt] = *(const bf16x8*)&Bc0[boff[nt]];
                    bm[nt] = *(const bf16x8*)&Bc1[boff[nt]];
                }
                #pragma unroll
                for (int half = 0; half < 2; ++half) {
                    bf16x8 ah[4], am[4];
                    #pragma unroll
                    for (int mt = 0; mt < 4; ++mt) {
                        ah[mt] = *(const bf16x8*)&Ac0[aoff[half * 4 + mt]];
                        am[mt] = *(const bf16x8*)&Ac1[aoff[half * 4 + mt]];
                    }
                    __builtin_amdgcn_s_setprio(1);
                    #pragma unroll
                    for (int nt = 0; nt < 4; ++nt) {
                        #pragma unroll
                        for (int mt = 0; mt < 4; ++mt) {
                            f32x4 a = acc[half * 4 + mt][nt];
                            a = __builtin_amdgcn_mfma_f32_16x16x32_bf16(am[mt], bh[nt], a, 0, 0, 0);
                            a = __builtin_amdgcn_mfma_f32_16x16x32_bf16(ah[mt], bm[nt], a, 0, 0, 0);
                            a = __builtin_amdgcn_mfma_f32_16x16x32_bf16(ah[mt], bh[nt], a, 0, 0, 0);
                            acc[half * 4 + mt][nt] = a;
                        }
                    }
                    __builtin_amdgcn_s_setprio(0);
                }

                if (ks < NK - 1)
                    asm volatile("s_waitcnt vmcnt(0)" ::: "memory");
                __builtin_amdgcn_s_barrier();
                __builtin_amdgcn_sched_barrier(0);
            }

            // bias + argmax -> atomicMax
            float bias[4];
            #pragma unroll
            for (int nt = 0; nt < 4; ++nt)
                bias[nt] = b2[nBase + wn * 64 + nt * 16 + lcol];

            #pragma unroll
            for (int mt = 0; mt < 8; ++mt) {
                #pragma unroll
                for (int r = 0; r < 4; ++r) {
                    unsigned long long best = 0ull;
                    #pragma unroll
                    for (int nt = 0; nt < 4; ++nt) {
                        int col = nBase + wn * 64 + nt * 16 + lcol;
                        float v = acc[mt][nt][r] + bias[nt];
                        unsigned long long p = packvi(v, col);
                        if (p > best) best = p;
                    }
                    #pragma unroll
                    for (int off = 1; off < 16; off <<= 1) {
                        unsigned long long o = __shfl_xor((long long)best, off, 64);
                        if (o > best) best = o;
                    }
                    if (lcol == 0) {
                        int row = mBase + wm * 128 + mt * 16 + quad * 4 + r;
                        atomicMax(&part[row], best);
                    }
                }
            }
        }
    }
    grid_sync(2);

    // ======================= phase D: gather =======================
    {
        int* js = (int*)SMEM;
        const int rbase = b * 128;
        if (tid < 128) {
            unsigned long long best = atomicAdd(&part[rbase + tid], 0ull);
            unsigned u = (unsigned)(best >> 32);
            float v = (u & 0x80000000u) ? __uint_as_float(u ^ 0x80000000u)
                                        : __uint_as_float(~u);
            int col = (int)(~(unsigned)best) & (C_DIM - 1);
            js[tid] = (v > 0.f) ? col : 0;  // all-nonpositive -> top_k picks 0
        }
        __syncthreads();
        const float4* LS4 = (const float4*)LS;
        float4* out4 = (float4*)out + (size_t)rbase * 128;
        #pragma unroll
        for (int i = 0; i < 32; ++i) {
            int idx = i * 512 + tid;            // [0, 16384)
            int row = idx >> 7, q = idx & 127;
            out4[idx] = LS4[(size_t)js[row] * 128 + q];
        }
    }
}

extern "C" void kernel_launch(void* const* d_in, const int* in_sizes, int n_in,
                              void* d_out, int out_size, void* d_ws, size_t ws_size,
                              hipStream_t stream) {
    const float* x     = (const float*)d_in[0];
    const float* i2m_w = (const float*)d_in[2];
    const float* i2m_b = (const float*)d_in[3];
    const float* m2h_w = (const float*)d_in[4];
    const float* m2h_b = (const float*)d_in[5];
    const float* h2o_w = (const float*)d_in[6];
    const float* h2o_b = (const float*)d_in[7];
    float* out = (float*)d_out;

    // ws layout (bytes), total exactly 4.75M:
    //   [0, 256K)        w1 hi plane   [256K, 512K)  w1 mid plane
    //   [512K, 1.5M)     w2 hi plane   [1.5M, 2.5M)  w2 mid plane
    //   [2.5M, 4.5M)     LS table (1024 x 512 fp32)
    //   [4.5M, 4.75M)    part: 32768 u64 (zeroed in phase A)
    char* ws = (char*)d_ws;
    ushort* w1h = (ushort*)(ws);
    ushort* w1m = (ushort*)(ws + 262144);
    ushort* w2h = (ushort*)(ws + 524288);
    ushort* w2m = (ushort*)(ws + 1572864);
    float*  LS  = (float*)(ws + 2621440);
    unsigned long long* part = (unsigned long long*)(ws + 4718592);

    // H planes live in d_out (2 x 32768*512 ushort = 64MB); phase D overwrites
    // d_out with the final fp32 output after all H readers are done.
    ushort* Hh = (ushort*)d_out;
    ushort* Hm = Hh + (size_t)M_ROWS * H_DIM;

    mega<<<256, 512, 0, stream>>>(x, i2m_w, i2m_b, m2h_w, m2h_b,
                                  h2o_w, h2o_b,
                                  w1h, w1m, w2h, w2m, LS, part,
                                  Hh, Hm, out);
}

// Round 10
// 261.220 us; speedup vs baseline: 1.1784x; 1.1784x over previous
//
#include <hip/hip_runtime.h>
#include <stdint.h>

#define M_ROWS 32768
#define I_DIM 256
#define H_DIM 512
#define C_DIM 1024
#define O_DIM 512

typedef __attribute__((ext_vector_type(8))) short bf16x8;
typedef __attribute__((ext_vector_type(4))) float f32x4;
typedef __attribute__((ext_vector_type(16))) float f32x16;

// ---------------------------------------------------------------------------
// 2-plane RNE split: x = hi + mid + r2, |r2| <= 2^-18 |x|.
// ---------------------------------------------------------------------------
__device__ __forceinline__ ushort bf16_rne(float f) {
    unsigned u = __float_as_uint(f);
    unsigned r = u + 0x7FFFu + ((u >> 16) & 1u);
    return (ushort)(r >> 16);
}
__device__ __forceinline__ float bf16_f32(ushort h) {
    return __uint_as_float(((unsigned)h) << 16);
}
__device__ __forceinline__ void split2(float f, ushort& hi, ushort& mid) {
    hi = bf16_rne(f);
    mid = bf16_rne(f - bf16_f32(hi));
}

__device__ __forceinline__ void async_ld16(const void* g, void* l) {
    __builtin_amdgcn_global_load_lds(
        (const __attribute__((address_space(1))) void*)g,
        (__attribute__((address_space(3))) void*)l, 16, 0, 0);
}

// Monotone packing: larger packed <=> (larger value, then smaller col index)
__device__ __forceinline__ unsigned long long packvi(float v, int col) {
    unsigned u = __float_as_uint(v);
    u = (u & 0x80000000u) ? ~u : (u | 0x80000000u);
    return ((unsigned long long)u << 32) | (unsigned)(~col);
}

// Swizzle: within each 64B k32-group of a row, 16B chunk kc sits at slot
// (kc + (row>>1)) & 3. Makes stride-64B fragment ds_read_b128 conflict-free
// while keeping rows DMA-contiguous (global_load_lds can't pad).
__device__ __forceinline__ int slot_of(int kc, int row) {
    return (kc + ((row >> 1) & 3)) & 3;
}

// ---------------------------------------------------------------------------
// prep: weight splits (permuted layout) + log-softmax table + part[] zero.
// ---------------------------------------------------------------------------
__global__ __launch_bounds__(256)
void prep(const float* __restrict__ W1, ushort* __restrict__ w1h, ushort* __restrict__ w1m,
          const float* __restrict__ W2, ushort* __restrict__ w2h, ushort* __restrict__ w2m,
          const float* __restrict__ Wo, const float* __restrict__ bo,
          float* __restrict__ LS, unsigned long long* __restrict__ part) {
    __shared__ float sred[4];
    const int b = blockIdx.x;
    const int t = threadIdx.x;
    if (b < 320) {
        const int isW1 = (b < 64);
        const float* W = isW1 ? W1 : W2;
        ushort* hh = isW1 ? w1h : w2h;
        ushort* mm = isW1 ? w1m : w2m;
        const int K = isW1 ? I_DIM : H_DIM;
        const int cpr = K >> 3;                       // chunks per row
        int gid = (isW1 ? b : b - 64) * 256 + t;      // chunk id
        int row = gid / cpr;
        int rem = gid - row * cpr;
        int g = rem >> 2, kc = rem & 3;
        float4 v0 = *(const float4*)(W + (size_t)gid * 8);
        float4 v1 = *(const float4*)(W + (size_t)gid * 8 + 4);
        __align__(16) ushort h[8], m[8];
        float f[8];
        *(float4*)&f[0] = v0; *(float4*)&f[4] = v1;
        #pragma unroll
        for (int j = 0; j < 8; ++j) split2(f[j], h[j], m[j]);
        size_t dst = (size_t)row * K + g * 32 + slot_of(kc, row) * 8;
        *(uint4*)(hh + dst) = *(uint4*)h;
        *(uint4*)(mm + dst) = *(uint4*)m;
    } else if (b < 1344) {
        const int j = b - 320;
        float l0 = Wo[(size_t)t * C_DIM + j] + bo[t];
        float l1 = Wo[(size_t)(t + 256) * C_DIM + j] + bo[t + 256];

        float mx = fmaxf(l0, l1);
        #pragma unroll
        for (int off = 1; off < 64; off <<= 1)
            mx = fmaxf(mx, __shfl_xor(mx, off, 64));
        if ((t & 63) == 0) sred[t >> 6] = mx;
        __syncthreads();
        mx = fmaxf(fmaxf(sred[0], sred[1]), fmaxf(sred[2], sred[3]));
        __syncthreads();

        float s = expf(l0 - mx) + expf(l1 - mx);
        #pragma unroll
        for (int off = 1; off < 64; off <<= 1)
            s += __shfl_xor(s, off, 64);
        if ((t & 63) == 0) sred[t >> 6] = s;
        __syncthreads();
        s = sred[0] + sred[1] + sred[2] + sred[3];

        float lse = mx + logf(s);
        LS[(size_t)j * O_DIM + t] = l0 - lse;
        LS[(size_t)j * O_DIM + t + 256] = l1 - lse;
    } else {
        part[(b - 1344) * 256 + t] = 0ull;
    }
}

// ---------------------------------------------------------------------------
// GEMM1: 256x256 tile, 512 threads (8 waves = 2m x 4n), BK=32, double-buffered
// 128KB LDS (single SMEM block, reused as 128KB epilogue staging).
// (round-5/8 proven structure, untouched)
// ---------------------------------------------------------------------------
__global__ __launch_bounds__(512, 2)
void gemm1_mfma(const float* __restrict__ X, const ushort* __restrict__ W1h,
                const ushort* __restrict__ W1m, const float* __restrict__ b1,
                ushort* __restrict__ Hh, ushort* __restrict__ Hm) {
    __shared__ __align__(16) ushort SMEM[65536];   // 128KB

    const int tid = threadIdx.x;
    const int lane = tid & 63, wave = tid >> 6;
    const int wm = wave >> 2, wn = wave & 3;          // 2m x 4n wave grid
    const int lcol = lane & 15, quad = lane >> 4;
    const int lrow = lane >> 2, lk = (lane & 3) * 8;

    // XCD swizzle: grid 256 = 128 mT x 2 nT; XCD d&7 owns 16 contiguous mT.
    const int d = blockIdx.x;
    const int q = d >> 3;
    const int mT = ((d & 7) << 4) + (q >> 1);
    const int nT = q & 1;
    const int mBase = mT * 256;
    const int nBase = nT * 256;

    const int s_row = tid >> 1, s_half = tid & 1;
    const int sl0 = slot_of(s_half * 2,     s_row);
    const int sl1 = slot_of(s_half * 2 + 1, s_row);
    const float* xrow = X + (size_t)(mBase + s_row) * I_DIM + s_half * 16;

    const int bplane = wave >> 2;
    const int brow0 = (wave & 3) * 64;
    const ushort* wp = bplane ? W1m : W1h;
    const ushort* gks = wp + (size_t)(nBase + brow0 + lrow) * I_DIM + lk;

    f32x4 acc[8][4];
    #pragma unroll
    for (int i = 0; i < 8; ++i)
        #pragma unroll
        for (int j = 0; j < 4; ++j)
            acc[i][j] = (f32x4){0.f, 0.f, 0.f, 0.f};

    int aoff[8], boff[4];
    #pragma unroll
    for (int t = 0; t < 8; ++t) {
        int ra = wm * 128 + t * 16 + lcol;
        aoff[t] = ra * 32 + slot_of(quad, ra) * 8;
    }
    #pragma unroll
    for (int t = 0; t < 4; ++t) {
        int rb = wn * 64 + t * 16 + lcol;
        boff[t] = rb * 32 + slot_of(quad, rb) * 8;
    }

    auto loadX = [&](float* f, int k0) {
        const float* ap = xrow + k0;
        *(float4*)&f[0]  = ((const float4*)ap)[0];
        *(float4*)&f[4]  = ((const float4*)ap)[1];
        *(float4*)&f[8]  = ((const float4*)ap)[2];
        *(float4*)&f[12] = ((const float4*)ap)[3];
    };
    auto stageB = [&](int buf, int k0) {
        ushort* bb = SMEM + 32768 + buf * 16384 + bplane * 8192 + brow0 * 32;
        #pragma unroll
        for (int j = 0; j < 4; ++j)
            async_ld16(gks + k0 + (size_t)(j * 16) * I_DIM, bb + j * 512);
    };
    auto writeA = [&](int buf, const float* f) {
        ushort* a0 = SMEM + buf * 16384;
        ushort* a1 = a0 + 8192;
        bf16x8 h0, h1, m0, m1;
        #pragma unroll
        for (int j = 0; j < 8; ++j) {
            ushort hu, mu;
            split2(f[j], hu, mu);
            h0[j] = (short)hu; m0[j] = (short)mu;
            split2(f[j + 8], hu, mu);
            h1[j] = (short)hu; m1[j] = (short)mu;
        }
        *(bf16x8*)&a0[s_row * 32 + sl0 * 8] = h0;
        *(bf16x8*)&a0[s_row * 32 + sl1 * 8] = h1;
        *(bf16x8*)&a1[s_row * 32 + sl0 * 8] = m0;
        *(bf16x8*)&a1[s_row * 32 + sl1 * 8] = m1;
    };

    {
        float fx[16];
        loadX(fx, 0);
        stageB(0, 0);
        writeA(0, fx);
    }
    asm volatile("s_waitcnt lgkmcnt(0)" ::: "memory");
    asm volatile("s_waitcnt vmcnt(0)" ::: "memory");
    __builtin_amdgcn_s_barrier();
    __builtin_amdgcn_sched_barrier(0);

    const int NK = I_DIM / 32;   // 8
    #pragma unroll 2
    for (int ks = 0; ks < NK; ++ks) {
        const int cur = ks & 1;
        const bool more = (ks + 1 < NK);
        const ushort* Ac0 = SMEM + cur * 16384;
        const ushort* Ac1 = Ac0 + 8192;
        const ushort* Bc0 = SMEM + 32768 + cur * 16384;
        const ushort* Bc1 = Bc0 + 8192;

        float fn[16];
        if (more) {
            loadX(fn, (ks + 1) * 32);
            stageB(cur ^ 1, (ks + 1) * 32);
            __builtin_amdgcn_sched_barrier(0);
        }

        bf16x8 bh[4], bm[4];
        #pragma unroll
        for (int nt = 0; nt < 4; ++nt) {
            bh[nt] = *(const bf16x8*)&Bc0[boff[nt]];
            bm[nt] = *(const bf16x8*)&Bc1[boff[nt]];
        }
        #pragma unroll
        for (int half = 0; half < 2; ++half) {
            bf16x8 ah[4], am[4];
            #pragma unroll
            for (int mt = 0; mt < 4; ++mt) {
                ah[mt] = *(const bf16x8*)&Ac0[aoff[half * 4 + mt]];
                am[mt] = *(const bf16x8*)&Ac1[aoff[half * 4 + mt]];
            }
            __builtin_amdgcn_s_setprio(1);
            #pragma unroll
            for (int nt = 0; nt < 4; ++nt) {
                #pragma unroll
                for (int mt = 0; mt < 4; ++mt) {
                    f32x4 a = acc[half * 4 + mt][nt];
                    a = __builtin_amdgcn_mfma_f32_16x16x32_bf16(am[mt], bh[nt], a, 0, 0, 0);
                    a = __builtin_amdgcn_mfma_f32_16x16x32_bf16(ah[mt], bm[nt], a, 0, 0, 0);
                    a = __builtin_amdgcn_mfma_f32_16x16x32_bf16(ah[mt], bh[nt], a, 0, 0, 0);
                    acc[half * 4 + mt][nt] = a;
                }
            }
            __builtin_amdgcn_s_setprio(0);
        }

        if (more) writeA(cur ^ 1, fn);
        asm volatile("s_waitcnt lgkmcnt(0)" ::: "memory");
        if (more)
            asm volatile("s_waitcnt vmcnt(0)" ::: "memory");
        __builtin_amdgcn_s_barrier();
        __builtin_amdgcn_sched_barrier(0);
    }

    // epilogue: bias+relu+split, staged across 128KB SMEM, coalesced uint4 out
    #pragma unroll
    for (int plane = 0; plane < 2; ++plane) {
        __syncthreads();
        #pragma unroll
        for (int nt = 0; nt < 4; ++nt) {
            int colRel = wn * 64 + nt * 16 + lcol;
            int g = colRel >> 5, kc = (colRel >> 3) & 3, pos = colRel & 7;
            float bias = b1[nBase + colRel];
            #pragma unroll
            for (int mt = 0; mt < 8; ++mt) {
                #pragma unroll
                for (int r = 0; r < 4; ++r) {
                    int rowRel = wm * 128 + mt * 16 + quad * 4 + r;
                    float v = fmaxf(acc[mt][nt][r] + bias, 0.f);
                    ushort hu, mu;
                    split2(v, hu, mu);
                    SMEM[rowRel * 256 + g * 32 + slot_of(kc, rowRel) * 8 + pos]
                        = plane ? mu : hu;
                }
            }
        }
        __syncthreads();
        ushort* dstp = plane ? Hm : Hh;
        #pragma unroll
        for (int l2 = 0; l2 < 16; ++l2) {
            int c = l2 * 512 + tid;
            int row = c >> 5, idx = c & 31;
            *(uint4*)(dstp + (size_t)(mBase + row) * H_DIM + nBase + idx * 8)
                = *(const uint4*)&SMEM[row * 256 + idx * 8];
        }
    }
}

// ---------------------------------------------------------------------------
// GEMM2: 256x256 tile, 512 threads (8 waves = 2m x 4n), BK=32, double-buffered
// 128KB LDS, depth-1 counted pipeline (r8 skeleton) -- inner product converted
// to v_mfma_f32_32x32x16_bf16: 48 MFMA/wave/step (was 96), ~18% less matrix-
// pipe time, halved issue pressure. Frag layout: row=lane&31, k-chunk=lane>>5
// (uniform extension of the working 16x16x32 pattern); C/D row/col mapping per
// guide m74/m101. ds_read stays 2-way-bank-free (16-lane quarters read 16
// consecutive rows, slot swizzle rotates per row-pair).
// ---------------------------------------------------------------------------
__global__ __launch_bounds__(512, 2)
void gemm2_mfma(const ushort* __restrict__ Hh, const ushort* __restrict__ Hm,
                const ushort* __restrict__ W2h, const ushort* __restrict__ W2m,
                const float* __restrict__ b2,
                unsigned long long* __restrict__ part) {
    __shared__ __align__(16) ushort As[2][2][8192];   // [buf][plane][256*32] 64KB
    __shared__ __align__(16) ushort Bs[2][2][8192];   // 64KB
    const int tid = threadIdx.x;
    const int lane = tid & 63, wave = tid >> 6;
    const int wm = wave >> 2, wn = wave & 3;          // 2m x 4n wave grid
    const int l31 = lane & 31, khalf = lane >> 5;     // 32x32 frag coords
    const int lrow = lane >> 2, lk = (lane & 3) * 8;

    // XCD swizzle: grid 512 = 128 mT x 4 nT. XCD x = d&7 owns mT [x*16,x*16+16)
    const int d = blockIdx.x;
    const int l = d >> 3;
    const int mT = ((d & 7) << 4) + (l >> 2);
    const int nT = l & 3;
    const int mBase = mT * 256;
    const int nBase = nT * 256;

    // staging role: m_id 0=Ah 1=Am 2=Bh 3=Bm; each wave stages 128 rows (8KB)
    const int m_id = wave >> 1;
    const int shalf = wave & 1;
    const ushort* gsrc;
    ushort* l0;
    ushort* l1;
    switch (m_id) {
        case 0:  gsrc = Hh  + (size_t)mBase * H_DIM; l0 = &As[0][0][0]; l1 = &As[1][0][0]; break;
        case 1:  gsrc = Hm  + (size_t)mBase * H_DIM; l0 = &As[0][1][0]; l1 = &As[1][1][0]; break;
        case 2:  gsrc = W2h + (size_t)nBase * H_DIM; l0 = &Bs[0][0][0]; l1 = &Bs[1][0][0]; break;
        default: gsrc = W2m + (size_t)nBase * H_DIM; l0 = &Bs[0][1][0]; l1 = &Bs[1][1][0]; break;
    }
    l0 += shalf * 4096;
    l1 += shalf * 4096;
    const ushort* gks = gsrc + (size_t)(shalf * 128 + lrow) * H_DIM + lk;

    // accumulators: 4 m-subtiles (32) x 2 n-subtiles (32), f32x16 each
    f32x16 acc[4][2];
    #pragma unroll
    for (int i = 0; i < 4; ++i)
        #pragma unroll
        for (int j = 0; j < 2; ++j)
            acc[i][j] = (f32x16)(0.f);

    // fragment LDS offsets: per (subtile, ksub): row = base + (lane&31),
    // k-chunk kc = ksub*2 + (lane>>5), 8 bf16 at swizzled slot.
    int aoff[4][2], boff[2][2];
    #pragma unroll
    for (int t = 0; t < 4; ++t) {
        int ra = wm * 128 + t * 32 + l31;
        #pragma unroll
        for (int ksb = 0; ksb < 2; ++ksb)
            aoff[t][ksb] = ra * 32 + slot_of(ksb * 2 + khalf, ra) * 8;
    }
    #pragma unroll
    for (int t = 0; t < 2; ++t) {
        int rb = wn * 64 + t * 32 + l31;
        #pragma unroll
        for (int ksb = 0; ksb < 2; ++ksb)
            boff[t][ksb] = rb * 32 + slot_of(ksb * 2 + khalf, rb) * 8;
    }

    auto stage = [&](ushort* lb, int k0) {
        #pragma unroll
        for (int j = 0; j < 8; ++j)
            async_ld16(gks + k0 + (size_t)(j * 16) * H_DIM, lb + j * 512);
    };

    // prologue: tile 0 -> buf 0
    stage(l0, 0);
    asm volatile("s_waitcnt vmcnt(0)" ::: "memory");
    __builtin_amdgcn_s_barrier();
    __builtin_amdgcn_sched_barrier(0);

    const int NK = H_DIM / 32;   // 16
    #pragma unroll 2
    for (int ks = 0; ks < NK; ++ks) {
        const int cur = ks & 1;
        if (ks < NK - 1) {
            stage(cur ? l0 : l1, (ks + 1) * 32);   // 8 DMA into other buffer
            __builtin_amdgcn_sched_barrier(0);     // keep issue early
        }

        #pragma unroll
        for (int ksb = 0; ksb < 2; ++ksb) {
            bf16x8 ah[4], am[4], bh[2], bm[2];
            #pragma unroll
            for (int mt = 0; mt < 4; ++mt) {
                ah[mt] = *(const bf16x8*)&As[cur][0][aoff[mt][ksb]];
                am[mt] = *(const bf16x8*)&As[cur][1][aoff[mt][ksb]];
            }
            #pragma unroll
            for (int nt = 0; nt < 2; ++nt) {
                bh[nt] = *(const bf16x8*)&Bs[cur][0][boff[nt][ksb]];
                bm[nt] = *(const bf16x8*)&Bs[cur][1][boff[nt][ksb]];
            }
            __builtin_amdgcn_s_setprio(1);
            #pragma unroll
            for (int nt = 0; nt < 2; ++nt) {
                #pragma unroll
                for (int mt = 0; mt < 4; ++mt) {
                    f32x16 a = acc[mt][nt];
                    a = __builtin_amdgcn_mfma_f32_32x32x16_bf16(am[mt], bh[nt], a, 0, 0, 0);
                    a = __builtin_amdgcn_mfma_f32_32x32x16_bf16(ah[mt], bm[nt], a, 0, 0, 0);
                    a = __builtin_amdgcn_mfma_f32_32x32x16_bf16(ah[mt], bh[nt], a, 0, 0, 0);
                    acc[mt][nt] = a;
                }
            }
            __builtin_amdgcn_s_setprio(0);
        }

        if (ks < NK - 1)
            asm volatile("s_waitcnt vmcnt(0)" ::: "memory");  // tile k+1 landed
        __builtin_amdgcn_s_barrier();       // all reads of buf[cur] consumed
        __builtin_amdgcn_sched_barrier(0);  // nothing crosses the boundary
    }

    // ---- epilogue: bias + argmax over this 256-col block -> atomicMax ----
    // C/D layout (m74/m101): col = l31, row = (reg&3) + 8*(reg>>2) + 4*khalf.
    float bias[2];
    #pragma unroll
    for (int nt = 0; nt < 2; ++nt)
        bias[nt] = b2[nBase + wn * 64 + nt * 32 + l31];

    #pragma unroll
    for (int mt = 0; mt < 4; ++mt) {
        #pragma unroll
        for (int reg = 0; reg < 16; ++reg) {
            unsigned long long best = 0ull;
            #pragma unroll
            for (int nt = 0; nt < 2; ++nt) {
                int col = nBase + wn * 64 + nt * 32 + l31;
                float v = acc[mt][nt][reg] + bias[nt];
                unsigned long long p = packvi(v, col);
                if (p > best) best = p;
            }
            // reduce over the 32-lane half (cols 0..31 of this row)
            #pragma unroll
            for (int off = 1; off < 32; off <<= 1) {
                unsigned long long o = __shfl_xor((long long)best, off, 64);
                if (o > best) best = o;
            }
            if (l31 == 0) {
                int row = mBase + wm * 128 + mt * 32
                        + (reg & 3) + 8 * (reg >> 2) + 4 * khalf;
                atomicMax(&part[row], best);
            }
        }
    }
}

// out[row,:] = LS[jstar(part[row]), :]; 8 rows per block
__global__ __launch_bounds__(256)
void gather_out(const unsigned long long* __restrict__ part,
                const float* __restrict__ LS, float* __restrict__ out) {
    __shared__ int js[8];
    const int tid = threadIdx.x;
    const int rbase = blockIdx.x * 8;
    if (tid < 8) {
        unsigned long long best = part[rbase + tid];
        unsigned u = (unsigned)(best >> 32);
        float v = (u & 0x80000000u) ? __uint_as_float(u ^ 0x80000000u)
                                    : __uint_as_float(~u);
        int col = (int)(~(unsigned)best) & (C_DIM - 1);
        js[tid] = (v > 0.f) ? col : 0;  // all-nonpositive -> top_k picks 0
    }
    __syncthreads();
    const float4* LS4 = (const float4*)LS;
    float4* out4 = (float4*)out + (size_t)rbase * 128;
    #pragma unroll
    for (int i = 0; i < 4; ++i) {
        int idx = i * 256 + tid;
        int row = idx >> 7, q = idx & 127;
        out4[idx] = LS4[(size_t)js[row] * 128 + q];
    }
}

extern "C" void kernel_launch(void* const* d_in, const int* in_sizes, int n_in,
                              void* d_out, int out_size, void* d_ws, size_t ws_size,
                              hipStream_t stream) {
    const float* x     = (const float*)d_in[0];
    const float* i2m_w = (const float*)d_in[2];
    const float* i2m_b = (const float*)d_in[3];
    const float* m2h_w = (const float*)d_in[4];
    const float* m2h_b = (const float*)d_in[5];
    const float* h2o_w = (const float*)d_in[6];
    const float* h2o_b = (const float*)d_in[7];
    float* out = (float*)d_out;

    // ws layout (bytes):
    //   [0, 256K)        w1 hi plane   [256K, 512K)  w1 mid plane
    //   [512K, 1.5M)     w2 hi plane   [1.5M, 2.5M)  w2 mid plane
    //   [2.5M, 4.5M)     LS table (1024 x 512 fp32)
    //   [4.5M, 4.75M)    part: 32768 u64 (atomicMax targets, zeroed in prep)
    char* ws = (char*)d_ws;
    ushort* w1h = (ushort*)(ws);
    ushort* w1m = (ushort*)(ws + 262144);
    ushort* w2h = (ushort*)(ws + 524288);
    ushort* w2m = (ushort*)(ws + 1572864);
    float*  LS  = (float*)(ws + 2621440);
    unsigned long long* part = (unsigned long long*)(ws + 4718592);

    // H planes live in d_out (2 x 32768*512 ushort = 64MB = exactly out_size*4B)
    ushort* Hh = (ushort*)d_out;
    ushort* Hm = Hh + (size_t)M_ROWS * H_DIM;

    prep<<<1472, 256, 0, stream>>>(i2m_w, w1h, w1m, m2h_w, w2h, w2m,
                                   h2o_w, h2o_b, LS, part);
    gemm1_mfma<<<(M_ROWS / 256) * (H_DIM / 256), 512, 0, stream>>>(
        x, w1h, w1m, i2m_b, Hh, Hm);
    gemm2_mfma<<<(M_ROWS / 256) * (C_DIM / 256), 512, 0, stream>>>(
        Hh, Hm, w2h, w2m, m2h_b, part);
    gather_out<<<M_ROWS / 8, 256, 0, stream>>>(part, LS, out);
}

// Round 11
// 236.850 us; speedup vs baseline: 1.2997x; 1.1029x over previous
//
#include <hip/hip_runtime.h>
#include <stdint.h>

#define M_ROWS 32768
#define I_DIM 256
#define H_DIM 512
#define C_DIM 1024
#define O_DIM 512

typedef __attribute__((ext_vector_type(8))) short bf16x8;
typedef __attribute__((ext_vector_type(4))) float f32x4;

// ---------------------------------------------------------------------------
// 2-plane RNE split: x = hi + mid + r2, |r2| <= 2^-18 |x|.
// ---------------------------------------------------------------------------
__device__ __forceinline__ ushort bf16_rne(float f) {
    unsigned u = __float_as_uint(f);
    unsigned r = u + 0x7FFFu + ((u >> 16) & 1u);
    return (ushort)(r >> 16);
}
__device__ __forceinline__ float bf16_f32(ushort h) {
    return __uint_as_float(((unsigned)h) << 16);
}
__device__ __forceinline__ void split2(float f, ushort& hi, ushort& mid) {
    hi = bf16_rne(f);
    mid = bf16_rne(f - bf16_f32(hi));
}

__device__ __forceinline__ void async_ld16(const void* g, void* l) {
    __builtin_amdgcn_global_load_lds(
        (const __attribute__((address_space(1))) void*)g,
        (__attribute__((address_space(3))) void*)l, 16, 0, 0);
}

// Monotone packing: larger packed <=> (larger value, then smaller col index)
__device__ __forceinline__ unsigned long long packvi(float v, int col) {
    unsigned u = __float_as_uint(v);
    u = (u & 0x80000000u) ? ~u : (u | 0x80000000u);
    return ((unsigned long long)u << 32) | (unsigned)(~col);
}

// Swizzle: within each 64B k32-group of a row, 16B chunk kc sits at slot
// (kc + (row>>1)) & 3. Makes stride-64B fragment ds_read_b128 conflict-free
// (2 lanes/bank-window for 16-row reads = free) while keeping rows
// DMA-contiguous (global_load_lds can't pad). NOTE: 32-row fragment reads
// (32x32 MFMA) are structurally >=4-way under this constraint -- measured
// 6.3M conflicts in round 10; do not revisit.
__device__ __forceinline__ int slot_of(int kc, int row) {
    return (kc + ((row >> 1) & 3)) & 3;
}

// ---------------------------------------------------------------------------
// prep: weight splits (permuted layout) + log-softmax table + part[] zero.
// ---------------------------------------------------------------------------
__global__ __launch_bounds__(256)
void prep(const float* __restrict__ W1, ushort* __restrict__ w1h, ushort* __restrict__ w1m,
          const float* __restrict__ W2, ushort* __restrict__ w2h, ushort* __restrict__ w2m,
          const float* __restrict__ Wo, const float* __restrict__ bo,
          float* __restrict__ LS, unsigned long long* __restrict__ part) {
    __shared__ float sred[4];
    const int b = blockIdx.x;
    const int t = threadIdx.x;
    if (b < 320) {
        const int isW1 = (b < 64);
        const float* W = isW1 ? W1 : W2;
        ushort* hh = isW1 ? w1h : w2h;
        ushort* mm = isW1 ? w1m : w2m;
        const int K = isW1 ? I_DIM : H_DIM;
        const int cpr = K >> 3;                       // chunks per row
        int gid = (isW1 ? b : b - 64) * 256 + t;      // chunk id
        int row = gid / cpr;
        int rem = gid - row * cpr;
        int g = rem >> 2, kc = rem & 3;
        float4 v0 = *(const float4*)(W + (size_t)gid * 8);
        float4 v1 = *(const float4*)(W + (size_t)gid * 8 + 4);
        __align__(16) ushort h[8], m[8];
        float f[8];
        *(float4*)&f[0] = v0; *(float4*)&f[4] = v1;
        #pragma unroll
        for (int j = 0; j < 8; ++j) split2(f[j], h[j], m[j]);
        size_t dst = (size_t)row * K + g * 32 + slot_of(kc, row) * 8;
        *(uint4*)(hh + dst) = *(uint4*)h;
        *(uint4*)(mm + dst) = *(uint4*)m;
    } else if (b < 1344) {
        const int j = b - 320;
        float l0 = Wo[(size_t)t * C_DIM + j] + bo[t];
        float l1 = Wo[(size_t)(t + 256) * C_DIM + j] + bo[t + 256];

        float mx = fmaxf(l0, l1);
        #pragma unroll
        for (int off = 1; off < 64; off <<= 1)
            mx = fmaxf(mx, __shfl_xor(mx, off, 64));
        if ((t & 63) == 0) sred[t >> 6] = mx;
        __syncthreads();
        mx = fmaxf(fmaxf(sred[0], sred[1]), fmaxf(sred[2], sred[3]));
        __syncthreads();

        float s = expf(l0 - mx) + expf(l1 - mx);
        #pragma unroll
        for (int off = 1; off < 64; off <<= 1)
            s += __shfl_xor(s, off, 64);
        if ((t & 63) == 0) sred[t >> 6] = s;
        __syncthreads();
        s = sred[0] + sred[1] + sred[2] + sred[3];

        float lse = mx + logf(s);
        LS[(size_t)j * O_DIM + t] = l0 - lse;
        LS[(size_t)j * O_DIM + t + 256] = l1 - lse;
    } else {
        part[(b - 1344) * 256 + t] = 0ull;
    }
}

// ---------------------------------------------------------------------------
// GEMM1: 256x256 tile, 512 threads (8 waves = 2m x 4n), BK=32, double-buffered
// 128KB LDS (single SMEM block, reused as 128KB epilogue staging).
// (round-5/8 proven structure)
// ---------------------------------------------------------------------------
__global__ __launch_bounds__(512, 2)
void gemm1_mfma(const float* __restrict__ X, const ushort* __restrict__ W1h,
                const ushort* __restrict__ W1m, const float* __restrict__ b1,
                ushort* __restrict__ Hh, ushort* __restrict__ Hm) {
    __shared__ __align__(16) ushort SMEM[65536];   // 128KB

    const int tid = threadIdx.x;
    const int lane = tid & 63, wave = tid >> 6;
    const int wm = wave >> 2, wn = wave & 3;          // 2m x 4n wave grid
    const int lcol = lane & 15, quad = lane >> 4;
    const int lrow = lane >> 2, lk = (lane & 3) * 8;

    // XCD swizzle: grid 256 = 128 mT x 2 nT; XCD d&7 owns 16 contiguous mT.
    const int d = blockIdx.x;
    const int q = d >> 3;
    const int mT = ((d & 7) << 4) + (q >> 1);
    const int nT = q & 1;
    const int mBase = mT * 256;
    const int nBase = nT * 256;

    const int s_row = tid >> 1, s_half = tid & 1;
    const int sl0 = slot_of(s_half * 2,     s_row);
    const int sl1 = slot_of(s_half * 2 + 1, s_row);
    const float* xrow = X + (size_t)(mBase + s_row) * I_DIM + s_half * 16;

    const int bplane = wave >> 2;
    const int brow0 = (wave & 3) * 64;
    const ushort* wp = bplane ? W1m : W1h;
    const ushort* gks = wp + (size_t)(nBase + brow0 + lrow) * I_DIM + lk;

    f32x4 acc[8][4];
    #pragma unroll
    for (int i = 0; i < 8; ++i)
        #pragma unroll
        for (int j = 0; j < 4; ++j)
            acc[i][j] = (f32x4){0.f, 0.f, 0.f, 0.f};

    int aoff[8], boff[4];
    #pragma unroll
    for (int t = 0; t < 8; ++t) {
        int ra = wm * 128 + t * 16 + lcol;
        aoff[t] = ra * 32 + slot_of(quad, ra) * 8;
    }
    #pragma unroll
    for (int t = 0; t < 4; ++t) {
        int rb = wn * 64 + t * 16 + lcol;
        boff[t] = rb * 32 + slot_of(quad, rb) * 8;
    }

    auto loadX = [&](float* f, int k0) {
        const float* ap = xrow + k0;
        *(float4*)&f[0]  = ((const float4*)ap)[0];
        *(float4*)&f[4]  = ((const float4*)ap)[1];
        *(float4*)&f[8]  = ((const float4*)ap)[2];
        *(float4*)&f[12] = ((const float4*)ap)[3];
    };
    auto stageB = [&](int buf, int k0) {
        ushort* bb = SMEM + 32768 + buf * 16384 + bplane * 8192 + brow0 * 32;
        #pragma unroll
        for (int j = 0; j < 4; ++j)
            async_ld16(gks + k0 + (size_t)(j * 16) * I_DIM, bb + j * 512);
    };
    auto writeA = [&](int buf, const float* f) {
        ushort* a0 = SMEM + buf * 16384;
        ushort* a1 = a0 + 8192;
        bf16x8 h0, h1, m0, m1;
        #pragma unroll
        for (int j = 0; j < 8; ++j) {
            ushort hu, mu;
            split2(f[j], hu, mu);
            h0[j] = (short)hu; m0[j] = (short)mu;
            split2(f[j + 8], hu, mu);
            h1[j] = (short)hu; m1[j] = (short)mu;
        }
        *(bf16x8*)&a0[s_row * 32 + sl0 * 8] = h0;
        *(bf16x8*)&a0[s_row * 32 + sl1 * 8] = h1;
        *(bf16x8*)&a1[s_row * 32 + sl0 * 8] = m0;
        *(bf16x8*)&a1[s_row * 32 + sl1 * 8] = m1;
    };

    {
        float fx[16];
        loadX(fx, 0);
        stageB(0, 0);
        writeA(0, fx);
    }
    asm volatile("s_waitcnt lgkmcnt(0)" ::: "memory");
    asm volatile("s_waitcnt vmcnt(0)" ::: "memory");
    __builtin_amdgcn_s_barrier();
    __builtin_amdgcn_sched_barrier(0);

    const int NK = I_DIM / 32;   // 8
    #pragma unroll 2
    for (int ks = 0; ks < NK; ++ks) {
        const int cur = ks & 1;
        const bool more = (ks + 1 < NK);
        const ushort* Ac0 = SMEM + cur * 16384;
        const ushort* Ac1 = Ac0 + 8192;
        const ushort* Bc0 = SMEM + 32768 + cur * 16384;
        const ushort* Bc1 = Bc0 + 8192;

        float fn[16];
        if (more) {
            loadX(fn, (ks + 1) * 32);        // X reg-loads in flight over MFMA
            stageB(cur ^ 1, (ks + 1) * 32);  // 4 DMA into other buffer
            __builtin_amdgcn_sched_barrier(0);
        }

        bf16x8 bh[4], bm[4];
        #pragma unroll
        for (int nt = 0; nt < 4; ++nt) {
            bh[nt] = *(const bf16x8*)&Bc0[boff[nt]];
            bm[nt] = *(const bf16x8*)&Bc1[boff[nt]];
        }
        #pragma unroll
        for (int half = 0; half < 2; ++half) {
            bf16x8 ah[4], am[4];
            #pragma unroll
            for (int mt = 0; mt < 4; ++mt) {
                ah[mt] = *(const bf16x8*)&Ac0[aoff[half * 4 + mt]];
                am[mt] = *(const bf16x8*)&Ac1[aoff[half * 4 + mt]];
            }
            __builtin_amdgcn_s_setprio(1);
            #pragma unroll
            for (int nt = 0; nt < 4; ++nt) {
                #pragma unroll
                for (int mt = 0; mt < 4; ++mt) {
                    f32x4 a = acc[half * 4 + mt][nt];
                    a = __builtin_amdgcn_mfma_f32_16x16x32_bf16(am[mt], bh[nt], a, 0, 0, 0);
                    a = __builtin_amdgcn_mfma_f32_16x16x32_bf16(ah[mt], bm[nt], a, 0, 0, 0);
                    a = __builtin_amdgcn_mfma_f32_16x16x32_bf16(ah[mt], bh[nt], a, 0, 0, 0);
                    acc[half * 4 + mt][nt] = a;
                }
            }
            __builtin_amdgcn_s_setprio(0);
        }

        if (more) writeA(cur ^ 1, fn);   // split VALU overlaps MFMA issue
        asm volatile("s_waitcnt lgkmcnt(0)" ::: "memory");  // reads+writes done
        if (more)
            asm volatile("s_waitcnt vmcnt(0)" ::: "memory"); // B DMAs landed
        __builtin_amdgcn_s_barrier();
        __builtin_amdgcn_sched_barrier(0);
    }

    // epilogue: bias+relu+split, staged across 128KB SMEM, coalesced uint4 out
    #pragma unroll
    for (int plane = 0; plane < 2; ++plane) {
        __syncthreads();
        #pragma unroll
        for (int nt = 0; nt < 4; ++nt) {
            int colRel = wn * 64 + nt * 16 + lcol;
            int g = colRel >> 5, kc = (colRel >> 3) & 3, pos = colRel & 7;
            float bias = b1[nBase + colRel];
            #pragma unroll
            for (int mt = 0; mt < 8; ++mt) {
                #pragma unroll
                for (int r = 0; r < 4; ++r) {
                    int rowRel = wm * 128 + mt * 16 + quad * 4 + r;
                    float v = fmaxf(acc[mt][nt][r] + bias, 0.f);
                    ushort hu, mu;
                    split2(v, hu, mu);
                    SMEM[rowRel * 256 + g * 32 + slot_of(kc, rowRel) * 8 + pos]
                        = plane ? mu : hu;
                }
            }
        }
        __syncthreads();
        ushort* dstp = plane ? Hm : Hh;
        #pragma unroll
        for (int l2 = 0; l2 < 16; ++l2) {
            int c = l2 * 512 + tid;
            int row = c >> 5, idx = c & 31;
            *(uint4*)(dstp + (size_t)(mBase + row) * H_DIM + nBase + idx * 8)
                = *(const uint4*)&SMEM[row * 256 + idx * 8];
        }
    }
}

// ---------------------------------------------------------------------------
// GEMM2: 256x256 tile, 512 threads (8 waves = 2m x 4n), BK=32, double-buffered
// 128KB LDS, depth-1 counted pipeline (round-3 proven core, ~104 us).
// ---------------------------------------------------------------------------
__global__ __launch_bounds__(512, 2)
void gemm2_mfma(const ushort* __restrict__ Hh, const ushort* __restrict__ Hm,
                const ushort* __restrict__ W2h, const ushort* __restrict__ W2m,
                const float* __restrict__ b2,
                unsigned long long* __restrict__ part) {
    __shared__ __align__(16) ushort As[2][2][8192];   // [buf][plane][256*32] 64KB
    __shared__ __align__(16) ushort Bs[2][2][8192];   // 64KB
    const int tid = threadIdx.x;
    const int lane = tid & 63, wave = tid >> 6;
    const int wm = wave >> 2, wn = wave & 3;          // 2m x 4n wave grid
    const int lcol = lane & 15, quad = lane >> 4;
    const int lrow = lane >> 2, lk = (lane & 3) * 8;

    // XCD swizzle: grid 512 = 128 mT x 4 nT. XCD x = d&7 owns mT [x*16,x*16+16),
    // nT fastest -> W2 (2MB) L2-resident, A-tile reused across the 4 nT.
    const int d = blockIdx.x;
    const int l = d >> 3;
    const int mT = ((d & 7) << 4) + (l >> 2);
    const int nT = l & 3;
    const int mBase = mT * 256;
    const int nBase = nT * 256;

    // staging role: m_id 0=Ah 1=Am 2=Bh 3=Bm; each wave stages 128 rows (8KB)
    const int m_id = wave >> 1;
    const int shalf = wave & 1;
    const ushort* gsrc;
    ushort* l0;
    ushort* l1;
    switch (m_id) {
        case 0:  gsrc = Hh  + (size_t)mBase * H_DIM; l0 = &As[0][0][0]; l1 = &As[1][0][0]; break;
        case 1:  gsrc = Hm  + (size_t)mBase * H_DIM; l0 = &As[0][1][0]; l1 = &As[1][1][0]; break;
        case 2:  gsrc = W2h + (size_t)nBase * H_DIM; l0 = &Bs[0][0][0]; l1 = &Bs[1][0][0]; break;
        default: gsrc = W2m + (size_t)nBase * H_DIM; l0 = &Bs[0][1][0]; l1 = &Bs[1][1][0]; break;
    }
    l0 += shalf * 4096;
    l1 += shalf * 4096;
    const ushort* gks = gsrc + (size_t)(shalf * 128 + lrow) * H_DIM + lk;

    f32x4 acc[8][4];
    #pragma unroll
    for (int i = 0; i < 8; ++i)
        #pragma unroll
        for (int j = 0; j < 4; ++j)
            acc[i][j] = (f32x4){0.f, 0.f, 0.f, 0.f};

    int aoff[8], boff[4];
    #pragma unroll
    for (int t = 0; t < 8; ++t) {
        int ra = wm * 128 + t * 16 + lcol;
        aoff[t] = ra * 32 + slot_of(quad, ra) * 8;
    }
    #pragma unroll
    for (int t = 0; t < 4; ++t) {
        int rb = wn * 64 + t * 16 + lcol;
        boff[t] = rb * 32 + slot_of(quad, rb) * 8;
    }

    auto stage = [&](ushort* lb, int k0) {
        #pragma unroll
        for (int j = 0; j < 8; ++j)
            async_ld16(gks + k0 + (size_t)(j * 16) * H_DIM, lb + j * 512);
    };

    // prologue: tile 0 -> buf 0
    stage(l0, 0);
    asm volatile("s_waitcnt vmcnt(0)" ::: "memory");
    __builtin_amdgcn_s_barrier();
    __builtin_amdgcn_sched_barrier(0);

    const int NK = H_DIM / 32;   // 16
    #pragma unroll 2
    for (int ks = 0; ks < NK; ++ks) {
        const int cur = ks & 1;
        if (ks < NK - 1) {
            stage(cur ? l0 : l1, (ks + 1) * 32);   // 8 DMA into other buffer
            __builtin_amdgcn_sched_barrier(0);     // keep issue early
        }

        // B fragments: read once, live across both m-halves
        bf16x8 bh[4], bm[4];
        #pragma unroll
        for (int nt = 0; nt < 4; ++nt) {
            bh[nt] = *(const bf16x8*)&Bs[cur][0][boff[nt]];
            bm[nt] = *(const bf16x8*)&Bs[cur][1][boff[nt]];
        }
        #pragma unroll
        for (int half = 0; half < 2; ++half) {
            bf16x8 ah[4], am[4];
            #pragma unroll
            for (int mt = 0; mt < 4; ++mt) {
                ah[mt] = *(const bf16x8*)&As[cur][0][aoff[half * 4 + mt]];
                am[mt] = *(const bf16x8*)&As[cur][1][aoff[half * 4 + mt]];
            }
            __builtin_amdgcn_s_setprio(1);
            #pragma unroll
            for (int nt = 0; nt < 4; ++nt) {
                #pragma unroll
                for (int mt = 0; mt < 4; ++mt) {
                    f32x4 a = acc[half * 4 + mt][nt];
                    a = __builtin_amdgcn_mfma_f32_16x16x32_bf16(am[mt], bh[nt], a, 0, 0, 0);
                    a = __builtin_amdgcn_mfma_f32_16x16x32_bf16(ah[mt], bm[nt], a, 0, 0, 0);
                    a = __builtin_amdgcn_mfma_f32_16x16x32_bf16(ah[mt], bh[nt], a, 0, 0, 0);
                    acc[half * 4 + mt][nt] = a;
                }
            }
            __builtin_amdgcn_s_setprio(0);
        }

        if (ks < NK - 1)
            asm volatile("s_waitcnt vmcnt(0)" ::: "memory");  // tile k+1 landed
        __builtin_amdgcn_s_barrier();       // all reads of buf[cur] consumed
        __builtin_amdgcn_sched_barrier(0);  // nothing crosses the boundary
    }

    // ---- epilogue: bias + argmax over this 256-col block -> atomicMax ----
    float bias[4];
    #pragma unroll
    for (int nt = 0; nt < 4; ++nt)
        bias[nt] = b2[nBase + wn * 64 + nt * 16 + lcol];

    #pragma unroll
    for (int mt = 0; mt < 8; ++mt) {
        #pragma unroll
        for (int r = 0; r < 4; ++r) {
            unsigned long long best = 0ull;
            #pragma unroll
            for (int nt = 0; nt < 4; ++nt) {
                int col = nBase + wn * 64 + nt * 16 + lcol;
                float v = acc[mt][nt][r] + bias[nt];
                unsigned long long p = packvi(v, col);
                if (p > best) best = p;
            }
            #pragma unroll
            for (int off = 1; off < 16; off <<= 1) {
                unsigned long long o = __shfl_xor((long long)best, off, 64);
                if (o > best) best = o;
            }
            if (lcol == 0) {
                int row = mBase + wm * 128 + mt * 16 + quad * 4 + r;
                atomicMax(&part[row], best);
            }
        }
    }
}

// out[row,:] = LS[jstar(part[row]), :]; 8 rows per block
__global__ __launch_bounds__(256)
void gather_out(const unsigned long long* __restrict__ part,
                const float* __restrict__ LS, float* __restrict__ out) {
    __shared__ int js[8];
    const int tid = threadIdx.x;
    const int rbase = blockIdx.x * 8;
    if (tid < 8) {
        unsigned long long best = part[rbase + tid];
        unsigned u = (unsigned)(best >> 32);
        float v = (u & 0x80000000u) ? __uint_as_float(u ^ 0x80000000u)
                                    : __uint_as_float(~u);
        int col = (int)(~(unsigned)best) & (C_DIM - 1);
        js[tid] = (v > 0.f) ? col : 0;  // all-nonpositive -> top_k picks 0
    }
    __syncthreads();
    const float4* LS4 = (const float4*)LS;
    float4* out4 = (float4*)out + (size_t)rbase * 128;
    #pragma unroll
    for (int i = 0; i < 4; ++i) {
        int idx = i * 256 + tid;
        int row = idx >> 7, q = idx & 127;
        out4[idx] = LS4[(size_t)js[row] * 128 + q];
    }
}

extern "C" void kernel_launch(void* const* d_in, const int* in_sizes, int n_in,
                              void* d_out, int out_size, void* d_ws, size_t ws_size,
                              hipStream_t stream) {
    const float* x     = (const float*)d_in[0];
    const float* i2m_w = (const float*)d_in[2];
    const float* i2m_b = (const float*)d_in[3];
    const float* m2h_w = (const float*)d_in[4];
    const float* m2h_b = (const float*)d_in[5];
    const float* h2o_w = (const float*)d_in[6];
    const float* h2o_b = (const float*)d_in[7];
    float* out = (float*)d_out;

    // ws layout (bytes):
    //   [0, 256K)        w1 hi plane   [256K, 512K)  w1 mid plane
    //   [512K, 1.5M)     w2 hi plane   [1.5M, 2.5M)  w2 mid plane
    //   [2.5M, 4.5M)     LS table (1024 x 512 fp32)
    //   [4.5M, 4.75M)    part: 32768 u64 (atomicMax targets, zeroed in prep)
    char* ws = (char*)d_ws;
    ushort* w1h = (ushort*)(ws);
    ushort* w1m = (ushort*)(ws + 262144);
    ushort* w2h = (ushort*)(ws + 524288);
    ushort* w2m = (ushort*)(ws + 1572864);
    float*  LS  = (float*)(ws + 2621440);
    unsigned long long* part = (unsigned long long*)(ws + 4718592);

    // H planes live in d_out (2 x 32768*512 ushort = 64MB = exactly out_size*4B)
    ushort* Hh = (ushort*)d_out;
    ushort* Hm = Hh + (size_t)M_ROWS * H_DIM;

    prep<<<1472, 256, 0, stream>>>(i2m_w, w1h, w1m, m2h_w, w2h, w2m,
                                   h2o_w, h2o_b, LS, part);
    gemm1_mfma<<<(M_ROWS / 256) * (H_DIM / 256), 512, 0, stream>>>(
        x, w1h, w1m, i2m_b, Hh, Hm);
    gemm2_mfma<<<(M_ROWS / 256) * (C_DIM / 256), 512, 0, stream>>>(
        Hh, Hm, w2h, w2m, m2h_b, part);
    gather_out<<<M_ROWS / 8, 256, 0, stream>>>(part, LS, out);
}